// Round 4
// baseline (404.560 us; speedup 1.0000x reference)
//
#include <hip/hip_runtime.h>
#include <cstddef>
#include <cstdint>

#define Bc 4
#define Nc 1024
#define Cc 768
#define Hc 12
#define Dc 64
#define BHc 48
#define QKV_ELEMS ((size_t)Bc * Nc * Cc)   // 3145728

typedef __attribute__((ext_vector_type(4))) unsigned int u32x4;
typedef __attribute__((ext_vector_type(8))) short s16x8;
typedef __attribute__((ext_vector_type(4))) float fx4;
typedef __attribute__((ext_vector_type(2))) float fx2;

union Frag { u32x4 u; s16x8 s; unsigned short h[8]; };

__device__ inline unsigned short f2bf(float x) {
    union { float f; uint32_t u; } c; c.f = x;
    return (unsigned short)((c.u + 0x7FFFu + ((c.u >> 16) & 1u)) >> 16);
}
__device__ inline float bf2f(unsigned short b) {
    union { uint32_t u; float f; } c; c.u = ((uint32_t)b) << 16;
    return c.f;
}
__device__ inline void split8(const float* v, u32x4& hi, u32x4& lo) {
    Frag fh, fl;
    #pragma unroll
    for (int e = 0; e < 8; ++e) {
        const unsigned short hb = f2bf(v[e]);
        fh.h[e] = hb;
        fl.h[e] = f2bf(v[e] - bf2f(hb));
    }
    hi = fh.u; lo = fl.u;
}

// ---------------------------------------------------------------------------
// prep_w: Wt_hi/lo[mat][n][k] = split(W[k][n])  (transpose + bf16 hi/lo split)
// ---------------------------------------------------------------------------
__global__ __launch_bounds__(256) void prep_w_kernel(
    const float* __restrict__ Wq, const float* __restrict__ Wk,
    const float* __restrict__ Wv, const float* __restrict__ Wo,
    unsigned short* __restrict__ Thi, unsigned short* __restrict__ Tlo)
{
    __shared__ float scr[64 * 65];
    const int mat = blockIdx.z;
    const float* W = (mat == 0) ? Wq : (mat == 1) ? Wk : (mat == 2) ? Wv : Wo;
    const int k0 = blockIdx.y * 64, n0 = blockIdx.x * 64;
    const int tid = threadIdx.x;

    #pragma unroll
    for (int it = 0; it < 4; ++it) {
        const int lin = tid + it * 256;
        const int r = lin >> 4, c4 = (lin & 15) << 2;
        const fx4 v = *(const fx4*)&W[(size_t)(k0 + r) * 768 + n0 + c4];
        scr[r * 65 + c4 + 0] = v[0]; scr[r * 65 + c4 + 1] = v[1];
        scr[r * 65 + c4 + 2] = v[2]; scr[r * 65 + c4 + 3] = v[3];
    }
    __syncthreads();
    unsigned short* th = Thi + (size_t)mat * 768 * 768;
    unsigned short* tl = Tlo + (size_t)mat * 768 * 768;
    #pragma unroll
    for (int it = 0; it < 16; ++it) {
        const int lin = tid + it * 256;
        const int n = lin >> 6, kq = lin & 63;
        const float val = scr[kq * 65 + n];
        const size_t o = (size_t)(n0 + n) * 768 + k0 + kq;
        const unsigned short hb = f2bf(val);
        th[o] = hb;
        tl[o] = f2bf(val - bf2f(hb));
    }
}

// ---------------------------------------------------------------------------
// prep_tables: PL tables + active-knot packing.
// idx = #{t: dist > knot_t} = n_neg + #{active knots < dist};  dist range
// [1e-3, 1.4142139]: knot < 0.00099 always-true, knot >= 1.41422 never-true.
// ---------------------------------------------------------------------------
__global__ __launch_bounds__(256) void prep_tables_kernel(
    const float* __restrict__ Wd1, const float* __restrict__ bd1,
    const float* __restrict__ Wd2, const float* __restrict__ bd2,
    float* __restrict__ abPack, float* __restrict__ kact, int* __restrict__ meta)
{
    __shared__ float w1s[16], b1s[16], kn[16];
    __shared__ int rank[16];
    const int tid = threadIdx.x;
    if (tid < 16) {
        const float w1 = Wd1[tid], b1 = bd1[tid];
        w1s[tid] = w1; b1s[tid] = b1;
        kn[tid] = (w1 != 0.0f) ? (-b1 / w1) : INFINITY;
    }
    __syncthreads();
    if (tid < 16) {
        int rk = 0;
        for (int u = 0; u < 16; ++u) {
            const float ku = kn[u], km = kn[tid];
            if (ku < km || (ku == km && u < tid)) ++rk;
        }
        rank[tid] = rk;
    }
    if (tid == 0) {
        int nn = 0, na = 0;
        for (int t = 0; t < 16; ++t) {
            const float kt = kn[t];
            if (kt < 0.00099f) ++nn;
            else if (kt < 1.41422f) kact[na++] = kt;
        }
        meta[0] = nn; meta[1] = na;
    }
    __syncthreads();
    if (tid < 17 * 12) {
        const int s = tid / 12, h = tid % 12;
        float a = 0.0f, be = bd2[h];
        for (int u = 0; u < 16; ++u) {
            const float w1 = w1s[u], b1 = b1s[u];
            bool act;
            if (w1 > 0.0f)      act = (rank[u] < s);
            else if (w1 < 0.0f) act = (rank[u] >= s);
            else                act = (b1 > 0.0f);
            if (act) {
                const float w2 = Wd2[u * 12 + h];
                a  += w2 * w1;
                be += w2 * b1;
            }
        }
        abPack[tid * 2 + 0] = a;
        abPack[tid * 2 + 1] = be;
    }
}

// ---------------------------------------------------------------------------
// split_x: x fp32 -> xhi/xlo bf16 row-major (one 8-chunk per thread)
// ---------------------------------------------------------------------------
__global__ __launch_bounds__(256) void split_x_kernel(
    const float* __restrict__ x, unsigned short* __restrict__ xhi,
    unsigned short* __restrict__ xlo)
{
    const size_t t = (size_t)blockIdx.x * 256 + threadIdx.x;   // < 393216
    float vv[8];
    const fx4 a = *(const fx4*)&x[t * 8];
    const fx4 b = *(const fx4*)&x[t * 8 + 4];
    vv[0]=a[0]; vv[1]=a[1]; vv[2]=a[2]; vv[3]=a[3];
    vv[4]=b[0]; vv[5]=b[1]; vv[6]=b[2]; vv[7]=b[3];
    u32x4 hi, lo; split8(vv, hi, lo);
    *(u32x4*)&xhi[t * 8] = hi;
    *(u32x4*)&xlo[t * 8] = lo;
}

// ---------------------------------------------------------------------------
// gemm_mfma: out = A[4096x768] @ W[768x768] + bias, bf16x3 via MFMA.
// AMODE 1: A = bf16 hi/lo row-major.  AMODE 2: A = P0+P1 (fp32 planes, split).
// OMODE 0: hi/lo head layout [bh][n][d]; OMODE 1: hi/lo vT [bh][d][n];
// OMODE 2: fp32 row-major.
// ---------------------------------------------------------------------------
struct SmemG { u32x4 ah[512]; u32x4 al[512]; u32x4 bh[512]; u32x4 bl[512]; };
struct SmemT { float scr[64 * 68]; };
union SmemU { SmemG g; SmemT t; };

template<int AMODE, int OMODE>
__global__ __launch_bounds__(256) void gemm_mfma_kernel(
    const unsigned short* __restrict__ Ahi, const unsigned short* __restrict__ Alo,
    const float* __restrict__ P0, const float* __restrict__ P1,
    const unsigned short* __restrict__ Bhi, const unsigned short* __restrict__ Blo,
    const float* __restrict__ bias,
    float* __restrict__ outF,
    unsigned short* __restrict__ Ohi, unsigned short* __restrict__ Olo)
{
    __shared__ SmemU sm;
    const int tid = threadIdx.x;
    const int w = tid >> 6, L = tid & 63;
    const int Lr = L & 15, Lg = L >> 4;
    const int m0 = blockIdx.y * 64, n0 = blockIdx.x * 64;

    fx4 acc[2][2] = {};

    for (int kk = 0; kk < 768; kk += 64) {
        #pragma unroll
        for (int it = 0; it < 2; ++it) {
            const int slot = tid + it * 256;
            const int s = slot >> 6, l = slot & 63;
            const int row = m0 + ((s >> 1) << 4) + (l & 15);
            const int kb = kk + ((s & 1) << 5) + ((l >> 4) << 3);
            if (AMODE == 1) {
                sm.g.ah[slot] = *(const u32x4*)&Ahi[(size_t)row * 768 + kb];
                sm.g.al[slot] = *(const u32x4*)&Alo[(size_t)row * 768 + kb];
            } else {
                const fx4 a0 = *(const fx4*)&P0[(size_t)row * 768 + kb];
                const fx4 a1 = *(const fx4*)&P0[(size_t)row * 768 + kb + 4];
                const fx4 c0 = *(const fx4*)&P1[(size_t)row * 768 + kb];
                const fx4 c1 = *(const fx4*)&P1[(size_t)row * 768 + kb + 4];
                float vv[8];
                vv[0]=a0[0]+c0[0]; vv[1]=a0[1]+c0[1]; vv[2]=a0[2]+c0[2]; vv[3]=a0[3]+c0[3];
                vv[4]=a1[0]+c1[0]; vv[5]=a1[1]+c1[1]; vv[6]=a1[2]+c1[2]; vv[7]=a1[3]+c1[3];
                u32x4 hi, lo; split8(vv, hi, lo);
                sm.g.ah[slot] = hi;
                sm.g.al[slot] = lo;
            }
            const int col = n0 + ((s >> 1) << 4) + (l & 63 & 15);
            sm.g.bh[slot] = *(const u32x4*)&Bhi[(size_t)col * 768 + kb];
            sm.g.bl[slot] = *(const u32x4*)&Blo[(size_t)col * 768 + kb];
        }
        __syncthreads();
        #pragma unroll
        for (int kc = 0; kc < 2; ++kc) {
            Frag ah[2], al[2], bh[2], bl[2];
            #pragma unroll
            for (int mm = 0; mm < 2; ++mm) {
                const int rg = (w >> 1) * 2 + mm;
                ah[mm].u = sm.g.ah[(rg * 2 + kc) * 64 + L];
                al[mm].u = sm.g.al[(rg * 2 + kc) * 64 + L];
            }
            #pragma unroll
            for (int nn = 0; nn < 2; ++nn) {
                const int cg = (w & 1) * 2 + nn;
                bh[nn].u = sm.g.bh[(cg * 2 + kc) * 64 + L];
                bl[nn].u = sm.g.bl[(cg * 2 + kc) * 64 + L];
            }
            #pragma unroll
            for (int mm = 0; mm < 2; ++mm)
                #pragma unroll
                for (int nn = 0; nn < 2; ++nn) {
                    acc[mm][nn] = __builtin_amdgcn_mfma_f32_16x16x32_bf16(ah[mm].s, bh[nn].s, acc[mm][nn], 0, 0, 0);
                    acc[mm][nn] = __builtin_amdgcn_mfma_f32_16x16x32_bf16(ah[mm].s, bl[nn].s, acc[mm][nn], 0, 0, 0);
                    acc[mm][nn] = __builtin_amdgcn_mfma_f32_16x16x32_bf16(al[mm].s, bh[nn].s, acc[mm][nn], 0, 0, 0);
                }
        }
        __syncthreads();
    }

    // stage (acc + bias) into scr[row][col], stride 68
    #pragma unroll
    for (int mm = 0; mm < 2; ++mm) {
        const int rl = (w >> 1) * 32 + mm * 16 + Lg * 4;
        #pragma unroll
        for (int nn = 0; nn < 2; ++nn) {
            const int cl = (w & 1) * 32 + nn * 16 + Lr;
            const float bs = bias[n0 + cl];
            #pragma unroll
            for (int r = 0; r < 4; ++r)
                sm.t.scr[(rl + r) * 68 + cl] = acc[mm][nn][r] + bs;
        }
    }
    __syncthreads();

    if (OMODE == 0) {
        const int h = n0 >> 6;
        #pragma unroll
        for (int it = 0; it < 2; ++it) {
            const int t = tid + it * 256;            // 512 slots
            const int r = t >> 3, d0 = (t & 7) << 3;
            float vv[8];
            #pragma unroll
            for (int e = 0; e < 8; ++e) vv[e] = sm.t.scr[r * 68 + d0 + e];
            u32x4 hi, lo; split8(vv, hi, lo);
            const int rg = m0 + r, b = rg >> 10, nloc = rg & 1023;
            const size_t o = (((size_t)(b * Hc + h) * Nc + nloc) << 6) + d0;
            *(u32x4*)&Ohi[o] = hi;
            *(u32x4*)&Olo[o] = lo;
        }
    } else if (OMODE == 1) {
        const int b = m0 >> 10, h = n0 >> 6, nbase = m0 & 1023;
        #pragma unroll
        for (int it = 0; it < 2; ++it) {
            const int t = tid + it * 256;
            const int dd = t >> 3, j0 = (t & 7) << 3;
            float vv[8];
            #pragma unroll
            for (int e = 0; e < 8; ++e) vv[e] = sm.t.scr[(j0 + e) * 68 + dd];
            u32x4 hi, lo; split8(vv, hi, lo);
            const size_t o = (size_t)((b * Hc + h) * Dc + dd) * Nc + nbase + j0;
            *(u32x4*)&Ohi[o] = hi;
            *(u32x4*)&Olo[o] = lo;
        }
    } else {
        #pragma unroll
        for (int it = 0; it < 4; ++it) {
            const int lin = tid + it * 256;
            const int r = lin >> 4, c4 = (lin & 15) << 2;
            const fx4 v = *(const fx4*)&sm.t.scr[r * 68 + c4];
            *(fx4*)&outF[(size_t)(m0 + r) * 768 + n0 + c4] = v;
        }
    }
}

// ---------------------------------------------------------------------------
// scores_half: swapped-operand QK^T (lane owns one q-row, j contiguous),
// PL-MLP spatial, raw scores -> attn, partial (m,l) per j-half -> ml.
// grid (16 i-tiles, 2 halves, 48 bh), 256 thr, wave = 16 q-rows.
// ---------------------------------------------------------------------------
__global__ __launch_bounds__(256, 4) void scores_half_kernel(
    const unsigned short* __restrict__ qhi, const unsigned short* __restrict__ qlo,
    const unsigned short* __restrict__ khi, const unsigned short* __restrict__ klo,
    const float* __restrict__ coords,
    const float* __restrict__ abPack, const float* __restrict__ kact,
    const int* __restrict__ meta,
    float* __restrict__ attn, float* __restrict__ ml)
{
    __shared__ u32x4 KsH[512], KsL[512];
    __shared__ fx2 cjs[512];
    __shared__ fx2 abt[17];
    __shared__ float kacts[16];
    __shared__ int metas[2];

    const int tid = threadIdx.x;
    const int w = tid >> 6, L = tid & 63;
    const int Lr = L & 15, Lg = L >> 4;
    const int bh = blockIdx.z, b = bh / Hc, h = bh % Hc;
    const int i0 = blockIdx.x * 64, half = blockIdx.y;
    const int i = i0 + w * 16 + Lr;
    const int Lg4 = Lg * 4;

    if (tid < 17) abt[tid] = *(const fx2*)&abPack[(tid * Hc + h) * 2];
    else if (tid >= 32 && tid < 48) kacts[tid - 32] = kact[tid - 32];
    else if (tid == 64) { metas[0] = meta[0]; metas[1] = meta[1]; }
    for (int t = tid; t < 512; t += 256)
        cjs[t] = *(const fx2*)&coords[((size_t)b * Nc + half * 512 + t) * 2];

    Frag qh[2], ql[2];
    #pragma unroll
    for (int kc = 0; kc < 2; ++kc) {
        const size_t o = ((size_t)bh * Nc + i) * 64 + kc * 32 + Lg * 8;
        qh[kc].u = *(const u32x4*)&qhi[o];
        ql[kc].u = *(const u32x4*)&qlo[o];
    }
    const fx2 ci = *(const fx2*)&coords[((size_t)b * Nc + i) * 2];
    __syncthreads();
    const int n_neg = metas[0], n_act = metas[1];

    float m_r = -INFINITY, l_r = 0.f;
    const size_t rowbase = ((size_t)bh * Nc + i) * Nc + half * 512;

    for (int jt = 0; jt < 8; ++jt) {
        #pragma unroll
        for (int it = 0; it < 2; ++it) {
            const int slot = tid + it * 256;
            const int s = slot >> 6, l = slot & 63;
            const int jrow = half * 512 + jt * 64 + ((s >> 1) << 4) + (l & 15);
            const int kb = ((s & 1) << 5) + ((l >> 4) << 3);
            const size_t o = ((size_t)bh * Nc + jrow) * 64 + kb;
            KsH[slot] = *(const u32x4*)&khi[o];
            KsL[slot] = *(const u32x4*)&klo[o];
        }
        __syncthreads();

        fx4 acc[4] = {};
        #pragma unroll
        for (int kc = 0; kc < 2; ++kc) {
            #pragma unroll
            for (int cg = 0; cg < 4; ++cg) {
                Frag kh_, kl_;
                kh_.u = KsH[(cg * 2 + kc) * 64 + L];
                kl_.u = KsL[(cg * 2 + kc) * 64 + L];
                // swapped operands: A = K (rows j), B = Q (cols i)
                acc[cg] = __builtin_amdgcn_mfma_f32_16x16x32_bf16(kh_.s, qh[kc].s, acc[cg], 0, 0, 0);
                acc[cg] = __builtin_amdgcn_mfma_f32_16x16x32_bf16(kl_.s, qh[kc].s, acc[cg], 0, 0, 0);
                acc[cg] = __builtin_amdgcn_mfma_f32_16x16x32_bf16(kh_.s, ql[kc].s, acc[cg], 0, 0, 0);
            }
        }

        float sv[16];
        #pragma unroll
        for (int cg = 0; cg < 4; ++cg) {
            float dist4[4]; int idx4[4];
            #pragma unroll
            for (int r = 0; r < 4; ++r) {
                const fx2 cj = cjs[jt * 64 + cg * 16 + Lg4 + r];
                const float dx = ci[0] - cj[0], dy = ci[1] - cj[1];
                dist4[r] = sqrtf(fmaf(dx, dx, fmaf(dy, dy, 1e-6f)));
                idx4[r] = n_neg;
            }
            for (int t = 0; t < n_act; ++t) {
                const float kt = kacts[t];
                #pragma unroll
                for (int r = 0; r < 4; ++r) idx4[r] += (dist4[r] > kt) ? 1 : 0;
            }
            #pragma unroll
            for (int r = 0; r < 4; ++r) {
                const fx2 ab = abt[idx4[r]];
                sv[cg * 4 + r] = fmaf(acc[cg][r], 0.125f, fmaf(ab[0], dist4[r], ab[1]));
            }
        }

        #pragma unroll
        for (int cg = 0; cg < 4; ++cg) {
            fx4 st;
            st[0] = sv[cg*4+0]; st[1] = sv[cg*4+1]; st[2] = sv[cg*4+2]; st[3] = sv[cg*4+3];
            *(fx4*)&attn[rowbase + jt * 64 + cg * 16 + Lg4] = st;
        }

        float tm = sv[0];
        #pragma unroll
        for (int e = 1; e < 16; ++e) tm = fmaxf(tm, sv[e]);
        tm = fmaxf(tm, __shfl_xor(tm, 16));
        tm = fmaxf(tm, __shfl_xor(tm, 32));
        const float mnew = fmaxf(m_r, tm);
        float ts = 0.f;
        #pragma unroll
        for (int e = 0; e < 16; ++e) ts += __expf(sv[e] - mnew);
        ts += __shfl_xor(ts, 16);
        ts += __shfl_xor(ts, 32);
        l_r = l_r * __expf(m_r - mnew) + ts;
        m_r = mnew;
        __syncthreads();
    }

    if (Lg == 0) {
        const size_t mo = (((size_t)bh * Nc + i) * 2 + half) * 2;
        ml[mo + 0] = m_r;
        ml[mo + 1] = l_r;
    }
}

// ---------------------------------------------------------------------------
// pv_half: combine (m,l) halves, p = exp(s-m)/l -> attn (in place, own cols),
// partial PV (fp32) -> Hp[half]. grid (16, 2, 48).
// ---------------------------------------------------------------------------
__global__ __launch_bounds__(256, 4) void pv_half_kernel(
    float* __restrict__ attn,
    const unsigned short* __restrict__ vThi, const unsigned short* __restrict__ vTlo,
    const float* __restrict__ ml,
    float* __restrict__ Hp)
{
    __shared__ u32x4 VsH[512], VsL[512];
    const int tid = threadIdx.x;
    const int w = tid >> 6, L = tid & 63;
    const int Lr = L & 15, Lg = L >> 4;
    const int bh = blockIdx.z, b = bh / Hc, h = bh % Hc;
    const int i0 = blockIdx.x * 64, half = blockIdx.y;
    const int wrow = i0 + w * 16;

    const size_t prow = (size_t)bh * Nc + wrow + Lr;
    const fx4 m4 = *(const fx4*)&ml[prow * 4];
    const float mm = fmaxf(m4[0], m4[2]);
    const float ll = m4[1] * __expf(m4[0] - mm) + m4[3] * __expf(m4[2] - mm);
    const float il = 1.0f / ll;

    fx4 acc[4] = {};

    for (int jt = 0; jt < 8; ++jt) {
        const int jglob = half * 8 + jt;
        #pragma unroll
        for (int it = 0; it < 2; ++it) {
            const int slot = tid + it * 256;
            const int s = slot >> 6, l = slot & 63;
            const int dd = ((s >> 1) << 4) + (l & 15);
            const int j = jglob * 64 + ((s & 1) << 5) + ((l >> 4) << 3);
            const size_t o = ((size_t)bh * Dc + dd) * Nc + j;
            VsH[slot] = *(const u32x4*)&vThi[o];
            VsL[slot] = *(const u32x4*)&vTlo[o];
        }
        __syncthreads();

        #pragma unroll
        for (int kc = 0; kc < 2; ++kc) {
            float* ap = &attn[prow * Nc + jglob * 64 + kc * 32 + Lg * 8];
            const fx4 s0 = *(const fx4*)ap;
            const fx4 s1 = *(const fx4*)(ap + 4);
            float p[8];
            p[0] = __expf(s0[0] - mm) * il; p[1] = __expf(s0[1] - mm) * il;
            p[2] = __expf(s0[2] - mm) * il; p[3] = __expf(s0[3] - mm) * il;
            p[4] = __expf(s1[0] - mm) * il; p[5] = __expf(s1[1] - mm) * il;
            p[6] = __expf(s1[2] - mm) * il; p[7] = __expf(s1[3] - mm) * il;
            fx4 w0, w1;
            w0[0]=p[0]; w0[1]=p[1]; w0[2]=p[2]; w0[3]=p[3];
            w1[0]=p[4]; w1[1]=p[5]; w1[2]=p[6]; w1[3]=p[7];
            *(fx4*)ap = w0;
            *(fx4*)(ap + 4) = w1;
            u32x4 phi, plo; split8(p, phi, plo);
            Frag ph, pl; ph.u = phi; pl.u = plo;
            #pragma unroll
            for (int dg = 0; dg < 4; ++dg) {
                Frag vh, vl;
                vh.u = VsH[(dg * 2 + kc) * 64 + L];
                vl.u = VsL[(dg * 2 + kc) * 64 + L];
                acc[dg] = __builtin_amdgcn_mfma_f32_16x16x32_bf16(ph.s, vh.s, acc[dg], 0, 0, 0);
                acc[dg] = __builtin_amdgcn_mfma_f32_16x16x32_bf16(ph.s, vl.s, acc[dg], 0, 0, 0);
                acc[dg] = __builtin_amdgcn_mfma_f32_16x16x32_bf16(pl.s, vh.s, acc[dg], 0, 0, 0);
            }
        }
        __syncthreads();
    }

    #pragma unroll
    for (int dg = 0; dg < 4; ++dg)
        #pragma unroll
        for (int r = 0; r < 4; ++r) {
            const int irow = wrow + Lg * 4 + r;
            Hp[(size_t)half * QKV_ELEMS + ((size_t)b * Nc + irow) * Cc + h * Dc + dg * 16 + Lr]
                = acc[dg][r];
        }
}

// ---------------------------------------------------------------------------
extern "C" void kernel_launch(void* const* d_in, const int* in_sizes, int n_in,
                              void* d_out, int out_size, void* d_ws, size_t ws_size,
                              hipStream_t stream)
{
    (void)in_sizes; (void)n_in; (void)out_size; (void)ws_size;

    const float* x      = (const float*)d_in[0];
    const float* coords = (const float*)d_in[1];
    const float* Wq = (const float*)d_in[2];  const float* bq = (const float*)d_in[3];
    const float* Wk = (const float*)d_in[4];  const float* bk = (const float*)d_in[5];
    const float* Wv = (const float*)d_in[6];  const float* bv = (const float*)d_in[7];
    const float* Wo = (const float*)d_in[8];  const float* bo = (const float*)d_in[9];
    const float* Wd1 = (const float*)d_in[10]; const float* bd1 = (const float*)d_in[11];
    const float* Wd2 = (const float*)d_in[12]; const float* bd2 = (const float*)d_in[13];

    float* out_main = (float*)d_out;            // [B,N,C]
    float* attn     = out_main + QKV_ELEMS;     // [B,H,N,N]

    uint8_t* wsb = (uint8_t*)d_ws;
    const size_t SZ_BF = (size_t)BHc * Nc * Dc * 2;          // 6,291,456 B
    const size_t SZ_W4 = (size_t)4 * 768 * 768 * 2;          // 4,718,592 B
    unsigned short* qhi  = (unsigned short*)(wsb + 0 * SZ_BF);
    unsigned short* qlo  = (unsigned short*)(wsb + 1 * SZ_BF);
    unsigned short* khi  = (unsigned short*)(wsb + 2 * SZ_BF);
    unsigned short* klo  = (unsigned short*)(wsb + 3 * SZ_BF);
    unsigned short* vThi = (unsigned short*)(wsb + 4 * SZ_BF);
    unsigned short* vTlo = (unsigned short*)(wsb + 5 * SZ_BF);
    float*          Hp   = (float*)(wsb + 0 * SZ_BF);        // aliases q/k (dead after scores)
    unsigned short* xhi  = (unsigned short*)(wsb + 6 * SZ_BF);
    unsigned short* xlo  = (unsigned short*)(wsb + 7 * SZ_BF);
    unsigned short* Thi  = (unsigned short*)(wsb + 8 * SZ_BF);
    unsigned short* Tlo  = (unsigned short*)(wsb + 8 * SZ_BF + SZ_W4);
    float* mlbuf  = (float*)(wsb + 8 * SZ_BF + 2 * SZ_W4);   // [BH*N][2 halves][2]
    float* abPack = mlbuf + (size_t)BHc * Nc * 4;            // 17*12*2
    float* kact   = abPack + 17 * 12 * 2;                    // 16
    int*   meta   = (int*)(kact + 16);                       // 2

    prep_w_kernel<<<dim3(12, 12, 4), 256, 0, stream>>>(Wq, Wk, Wv, Wo, Thi, Tlo);
    prep_tables_kernel<<<1, 256, 0, stream>>>(Wd1, bd1, Wd2, bd2, abPack, kact, meta);
    split_x_kernel<<<dim3(1536), 256, 0, stream>>>(x, xhi, xlo);

    dim3 gGemm(12, 64);
    gemm_mfma_kernel<1, 0><<<gGemm, 256, 0, stream>>>(
        xhi, xlo, nullptr, nullptr, Thi + (size_t)0 * 768 * 768, Tlo + (size_t)0 * 768 * 768,
        bq, nullptr, qhi, qlo);
    gemm_mfma_kernel<1, 0><<<gGemm, 256, 0, stream>>>(
        xhi, xlo, nullptr, nullptr, Thi + (size_t)1 * 768 * 768, Tlo + (size_t)1 * 768 * 768,
        bk, nullptr, khi, klo);
    gemm_mfma_kernel<1, 1><<<gGemm, 256, 0, stream>>>(
        xhi, xlo, nullptr, nullptr, Thi + (size_t)2 * 768 * 768, Tlo + (size_t)2 * 768 * 768,
        bv, nullptr, vThi, vTlo);

    scores_half_kernel<<<dim3(16, 2, 48), 256, 0, stream>>>(
        qhi, qlo, khi, klo, coords, abPack, kact, meta, attn, mlbuf);

    pv_half_kernel<<<dim3(16, 2, 48), 256, 0, stream>>>(
        attn, vThi, vTlo, mlbuf, Hp);

    gemm_mfma_kernel<2, 2><<<gGemm, 256, 0, stream>>>(
        nullptr, nullptr, Hp, Hp + QKV_ELEMS, Thi + (size_t)3 * 768 * 768,
        Tlo + (size_t)3 * 768 * 768, bo, out_main, nullptr, nullptr);
}